// Round 7
// baseline (87.666 us; speedup 1.0000x reference)
//
#include <hip/hip_runtime.h>
#include <hip/hip_bf16.h>

#define BATCH 4
#define S_LEN 2048
#define D_MOD 256
#define NH 8
#define HDIM 32
#define SCALE_ 0.0625f
#define QLOG2E 0.09016844f   // SCALE_ * log2(e); folded into Q at projection

typedef short bf16x8 __attribute__((ext_vector_type(8)));
typedef short short4v __attribute__((ext_vector_type(4)));
typedef float f32x4 __attribute__((ext_vector_type(4)));

__device__ __forceinline__ short f2bf(float f) {
    __hip_bfloat16 h = __float2bfloat16(f);
    return *reinterpret_cast<short*>(&h);
}

// ---------------------------------------------------------------------------
// K0: W fp32 [k][n] -> WT bf16 [n][k] for Wq,Wk,Wv,Wo.  grid (4, 32).
// ---------------------------------------------------------------------------
__global__ __launch_bounds__(256) void wtrans_kernel(
    const float* __restrict__ Wq, const float* __restrict__ Wk,
    const float* __restrict__ Wv, const float* __restrict__ Wo,
    short* __restrict__ WT)
{
    const int wsel = blockIdx.x;
    const int k0 = blockIdx.y * 8;
    const float* W = wsel == 0 ? Wq : (wsel == 1 ? Wk : (wsel == 2 ? Wv : Wo));
    short* T = WT + (size_t)wsel * 256 * 256;
    int n = threadIdx.x;
    bf16x8 o;
    #pragma unroll
    for (int kk = 0; kk < 8; ++kk)
        o[kk] = f2bf(W[(size_t)(k0 + kk) * 256 + n]);
    *(bf16x8*)&T[(size_t)n * 256 + k0] = o;
}

// ---------------------------------------------------------------------------
// K1: QKV projection, streaming.  Q is PRE-SCALED by SCALE*log2e so the
// attention kernel can use exp2 directly.  Q,K packed [bh][s][32];
// V transposed [bh][hd][s].  grid (256, 3).
// ---------------------------------------------------------------------------
__global__ __launch_bounds__(256) void qkv_proj_kernel(
    const float* __restrict__ q_in, const float* __restrict__ k_in,
    const float* __restrict__ v_in, const short* __restrict__ WT,
    const float* __restrict__ bq, const float* __restrict__ bk,
    const float* __restrict__ bv,
    short* __restrict__ Qp, short* __restrict__ Kp, short* __restrict__ Vt)
{
    __shared__ short lsA[32][264];
    const int mt = blockIdx.x;
    const int seg = blockIdx.y;
    const float* A = seg == 0 ? q_in : (seg == 1 ? k_in : v_in);
    const short* WTs = WT + (size_t)seg * 65536;
    const float* bias = seg == 0 ? bq : (seg == 1 ? bk : bv);
    const int m0 = mt * 32;
    const int tid = threadIdx.x;

    {
        const float4* A4 = (const float4*)(A + (size_t)m0 * D_MOD);
        #pragma unroll
        for (int i = 0; i < 8; ++i) {
            int f4 = tid + i * 256;
            int row = f4 >> 6, c4 = f4 & 63;
            float4 v = A4[f4];
            short4v o;
            o.x = f2bf(v.x); o.y = f2bf(v.y); o.z = f2bf(v.z); o.w = f2bf(v.w);
            *(short4v*)&lsA[row][c4 * 4] = o;
        }
    }
    __syncthreads();

    const int w = tid >> 6, l = tid & 63, g = l >> 4, r15 = l & 15;
    bf16x8 af[2][8];
    #pragma unroll
    for (int f = 0; f < 2; ++f)
        #pragma unroll
        for (int kk = 0; kk < 8; ++kk)
            af[f][kk] = *(const bf16x8*)&lsA[f * 16 + r15][kk * 32 + 8 * g];

    const int bidx = m0 >> 11;
    const int s_base = m0 & (S_LEN - 1);

    #pragma unroll
    for (int ntl = 0; ntl < 4; ++ntl) {
        int col = w * 64 + ntl * 16 + r15;
        f32x4 acc0 = {}, acc1 = {};
        #pragma unroll
        for (int kk = 0; kk < 8; ++kk) {
            bf16x8 b = *(const bf16x8*)&WTs[(size_t)col * 256 + kk * 32 + 8 * g];
            acc0 = __builtin_amdgcn_mfma_f32_16x16x32_bf16(af[0][kk], b, acc0, 0, 0, 0);
            acc1 = __builtin_amdgcn_mfma_f32_16x16x32_bf16(af[1][kk], b, acc1, 0, 0, 0);
        }
        float bval = bias[col];
        int h = col >> 5, hd = col & 31;
        if (seg == 0) {
            short* Outh = Qp + ((size_t)(bidx * NH + h) * S_LEN) * HDIM;
            #pragma unroll
            for (int r = 0; r < 4; ++r) {
                int s0 = s_base + 4 * g + r;
                Outh[(size_t)s0 * HDIM + hd]        = f2bf((acc0[r] + bval) * QLOG2E);
                Outh[(size_t)(s0 + 16) * HDIM + hd] = f2bf((acc1[r] + bval) * QLOG2E);
            }
        } else if (seg == 1) {
            short* Outh = Kp + ((size_t)(bidx * NH + h) * S_LEN) * HDIM;
            #pragma unroll
            for (int r = 0; r < 4; ++r) {
                int s0 = s_base + 4 * g + r;
                Outh[(size_t)s0 * HDIM + hd]        = f2bf(acc0[r] + bval);
                Outh[(size_t)(s0 + 16) * HDIM + hd] = f2bf(acc1[r] + bval);
            }
        } else {
            short* Vh = Vt + ((size_t)(bidx * NH + h) * HDIM + hd) * S_LEN;
            short4v o0, o1;
            #pragma unroll
            for (int r = 0; r < 4; ++r) { o0[r] = f2bf(acc0[r] + bval); o1[r] = f2bf(acc1[r] + bval); }
            size_t s = s_base + 4 * g;
            *(short4v*)&Vh[s]      = o0;
            *(short4v*)&Vh[s + 16] = o1;
        }
    }
}

// ---------------------------------------------------------------------------
// K2: causal attention, PAIRED q-tiles for uniform block work.
// Block = 4 waves, all on (bh, q-tiles {63-t, t}); every block ~34 k-tiles.
// Light tile's key range is a subset of heavy's -> K/V fragments shared.
// Q pre-scaled -> P = exp2(S).  grid 1024 (4 blocks/CU, all resident).
// ---------------------------------------------------------------------------
__global__ __launch_bounds__(256, 4) void attn_kernel(
    const short* __restrict__ Qp, const short* __restrict__ Kp,
    const short* __restrict__ Vt, short* __restrict__ Ab)
{
    __shared__ short pl[4][64][72];            // 36,864 B; unioned with comb
    __shared__ float psl[4][4][16];            // per-wave row sums
    float (*comb)[64][33] = (float(*)[64][33])pl;

    const int idx = blockIdx.x;
    const int bh = 4 * (idx & 7) + ((idx >> 3) & 3);   // XCD-local bh groups
    const int t  = idx >> 5;                   // 0..31
    const int b = bh >> 3, h = bh & 7;
    const int tid = threadIdx.x;
    const int w = tid >> 6, l = tid & 63, g = l >> 4, r15 = l & 15;
    const int q0b = (63 - t) * 32;             // heavy q-tile
    const int q0s = t * 32;                    // light q-tile

    const short* Qph = Qp + (size_t)bh * S_LEN * HDIM;
    const short* Kph = Kp + (size_t)bh * S_LEN * HDIM;
    const short* Vtp = Vt + (size_t)bh * HDIM * S_LEN;

    bf16x8 aqb0 = *(const bf16x8*)&Qph[(size_t)(q0b + r15) * HDIM + 8 * g];
    bf16x8 aqb1 = *(const bf16x8*)&Qph[(size_t)(q0b + 16 + r15) * HDIM + 8 * g];
    bf16x8 aqs0 = *(const bf16x8*)&Qph[(size_t)(q0s + r15) * HDIM + 8 * g];
    bf16x8 aqs1 = *(const bf16x8*)&Qph[(size_t)(q0s + 16 + r15) * HDIM + 8 * g];

    f32x4 ob[2][2] = {}, os[2][2] = {};
    float psb0[4] = {}, psb1[4] = {}, pss0[4] = {}, pss1[4] = {};
    const f32x4 zero = {};
    const int ntb = (q0b + 95) >> 6;
    const int nts = (q0s + 95) >> 6;

    for (int kt = w; kt < ntb; kt += 4) {
        const int k0 = kt * 64;
        const bool son = kt < nts;             // light tile active (uniform)
        const bool fb = (k0 + 63) <= q0b;
        const bool fs = (k0 + 63) <= q0s;

        bf16x8 bk[4];
        #pragma unroll
        for (int n = 0; n < 4; ++n)
            bk[n] = *(const bf16x8*)&Kph[(size_t)(k0 + n * 16 + r15) * HDIM + 8 * g];

        // QK^T + exp2 + P-store, fused per n to bound register live range
        #pragma unroll
        for (int n = 0; n < 4; ++n) {
            const int key = k0 + n * 16 + r15;
            __builtin_amdgcn_s_setprio(1);
            f32x4 s0 = __builtin_amdgcn_mfma_f32_16x16x32_bf16(aqb0, bk[n], zero, 0, 0, 0);
            f32x4 s1 = __builtin_amdgcn_mfma_f32_16x16x32_bf16(aqb1, bk[n], zero, 0, 0, 0);
            __builtin_amdgcn_s_setprio(0);
            if (fb) {
                #pragma unroll
                for (int r = 0; r < 4; ++r) {
                    float e0 = exp2f(s0[r]);
                    float e1 = exp2f(s1[r]);
                    psb0[r] += e0; psb1[r] += e1;
                    pl[w][4 * g + r][n * 16 + r15]      = f2bf(e0);
                    pl[w][16 + 4 * g + r][n * 16 + r15] = f2bf(e1);
                }
            } else {
                #pragma unroll
                for (int r = 0; r < 4; ++r) {
                    int qr = q0b + 4 * g + r;
                    float e0 = (key <= qr)      ? exp2f(s0[r]) : 0.0f;
                    float e1 = (key <= qr + 16) ? exp2f(s1[r]) : 0.0f;
                    psb0[r] += e0; psb1[r] += e1;
                    pl[w][4 * g + r][n * 16 + r15]      = f2bf(e0);
                    pl[w][16 + 4 * g + r][n * 16 + r15] = f2bf(e1);
                }
            }
            if (son) {
                __builtin_amdgcn_s_setprio(1);
                f32x4 u0 = __builtin_amdgcn_mfma_f32_16x16x32_bf16(aqs0, bk[n], zero, 0, 0, 0);
                f32x4 u1 = __builtin_amdgcn_mfma_f32_16x16x32_bf16(aqs1, bk[n], zero, 0, 0, 0);
                __builtin_amdgcn_s_setprio(0);
                if (fs) {
                    #pragma unroll
                    for (int r = 0; r < 4; ++r) {
                        float e0 = exp2f(u0[r]);
                        float e1 = exp2f(u1[r]);
                        pss0[r] += e0; pss1[r] += e1;
                        pl[w][32 + 4 * g + r][n * 16 + r15] = f2bf(e0);
                        pl[w][48 + 4 * g + r][n * 16 + r15] = f2bf(e1);
                    }
                } else {
                    #pragma unroll
                    for (int r = 0; r < 4; ++r) {
                        int qr = q0s + 4 * g + r;
                        float e0 = (key <= qr)      ? exp2f(u0[r]) : 0.0f;
                        float e1 = (key <= qr + 16) ? exp2f(u1[r]) : 0.0f;
                        pss0[r] += e0; pss1[r] += e1;
                        pl[w][32 + 4 * g + r][n * 16 + r15] = f2bf(e0);
                        pl[w][48 + 4 * g + r][n * 16 + r15] = f2bf(e1);
                    }
                }
            }
        }

        // V fragments (shared by heavy and light PV)
        bf16x8 bv[2][2];
        #pragma unroll
        for (int n2 = 0; n2 < 2; ++n2)
            #pragma unroll
            for (int ks = 0; ks < 2; ++ks)
                bv[n2][ks] = *(const bf16x8*)&Vtp[(size_t)(n2 * 16 + r15) * S_LEN + k0 + ks * 32 + 8 * g];

        __builtin_amdgcn_s_setprio(1);
        #pragma unroll
        for (int ks = 0; ks < 2; ++ks) {
            bf16x8 pb0 = *(const bf16x8*)&pl[w][r15][ks * 32 + 8 * g];
            bf16x8 pb1 = *(const bf16x8*)&pl[w][16 + r15][ks * 32 + 8 * g];
            #pragma unroll
            for (int n2 = 0; n2 < 2; ++n2) {
                ob[0][n2] = __builtin_amdgcn_mfma_f32_16x16x32_bf16(pb0, bv[n2][ks], ob[0][n2], 0, 0, 0);
                ob[1][n2] = __builtin_amdgcn_mfma_f32_16x16x32_bf16(pb1, bv[n2][ks], ob[1][n2], 0, 0, 0);
            }
        }
        if (son) {
            #pragma unroll
            for (int ks = 0; ks < 2; ++ks) {
                bf16x8 pc0 = *(const bf16x8*)&pl[w][32 + r15][ks * 32 + 8 * g];
                bf16x8 pc1 = *(const bf16x8*)&pl[w][48 + r15][ks * 32 + 8 * g];
                #pragma unroll
                for (int n2 = 0; n2 < 2; ++n2) {
                    os[0][n2] = __builtin_amdgcn_mfma_f32_16x16x32_bf16(pc0, bv[n2][ks], os[0][n2], 0, 0, 0);
                    os[1][n2] = __builtin_amdgcn_mfma_f32_16x16x32_bf16(pc1, bv[n2][ks], os[1][n2], 0, 0, 0);
                }
            }
        }
        __builtin_amdgcn_s_setprio(0);
    }

    // row-sum reduce across the 16 key-lanes of each group
    #pragma unroll
    for (int r = 0; r < 4; ++r) {
        float v0 = psb0[r], v1 = psb1[r], v2 = pss0[r], v3 = pss1[r];
        v0 += __shfl_xor(v0, 1); v1 += __shfl_xor(v1, 1); v2 += __shfl_xor(v2, 1); v3 += __shfl_xor(v3, 1);
        v0 += __shfl_xor(v0, 2); v1 += __shfl_xor(v1, 2); v2 += __shfl_xor(v2, 2); v3 += __shfl_xor(v3, 2);
        v0 += __shfl_xor(v0, 4); v1 += __shfl_xor(v1, 4); v2 += __shfl_xor(v2, 4); v3 += __shfl_xor(v3, 4);
        v0 += __shfl_xor(v0, 8); v1 += __shfl_xor(v1, 8); v2 += __shfl_xor(v2, 8); v3 += __shfl_xor(v3, 8);
        psb0[r] = v0; psb1[r] = v1; pss0[r] = v2; pss1[r] = v3;
    }
    if (r15 == 0) {
        #pragma unroll
        for (int r = 0; r < 4; ++r) {
            psl[w][0][4 * g + r] = psb0[r];
            psl[w][1][4 * g + r] = psb1[r];
            psl[w][2][4 * g + r] = pss0[r];
            psl[w][3][4 * g + r] = pss1[r];
        }
    }
    __syncthreads();   // all PV reads of pl done -> reuse storage as comb

    #pragma unroll
    for (int n2 = 0; n2 < 2; ++n2) {
        #pragma unroll
        for (int r = 0; r < 4; ++r) {
            comb[w][4 * g + r][n2 * 16 + r15]      = ob[0][n2][r];
            comb[w][16 + 4 * g + r][n2 * 16 + r15] = ob[1][n2][r];
            comb[w][32 + 4 * g + r][n2 * 16 + r15] = os[0][n2][r];
            comb[w][48 + 4 * g + r][n2 * 16 + r15] = os[1][n2][r];
        }
    }
    __syncthreads();

    // epilogue: 256 threads cover 64 q-rows x 32 hd (8 floats each)
    {
        int q = tid >> 2, hd0 = (tid & 3) * 8;
        float ps = psl[0][q >> 4][q & 15] + psl[1][q >> 4][q & 15]
                 + psl[2][q >> 4][q & 15] + psl[3][q >> 4][q & 15];
        float inv = __fdividef(1.0f, ps);
        int row = (q < 32) ? (q0b + q) : (q0s + q - 32);
        bf16x8 o;
        #pragma unroll
        for (int j = 0; j < 8; ++j) {
            float v = comb[0][q][hd0 + j] + comb[1][q][hd0 + j]
                    + comb[2][q][hd0 + j] + comb[3][q][hd0 + j];
            o[j] = f2bf(v * inv);
        }
        *(bf16x8*)&Ab[((size_t)b * S_LEN + row) * D_MOD + h * HDIM + hd0] = o;
    }
}

// ---------------------------------------------------------------------------
// K3: output projection, streaming (no LDS).  grid 256.
// ---------------------------------------------------------------------------
__global__ __launch_bounds__(256) void out_proj_kernel(
    const short* __restrict__ Ab, const short* __restrict__ WTo,
    const float* __restrict__ bo, float* __restrict__ out)
{
    const int m0 = blockIdx.x * 32;
    const int tid = threadIdx.x;
    const int w = tid >> 6, l = tid & 63, g = l >> 4, r15 = l & 15;

    bf16x8 af[2][8];
    #pragma unroll
    for (int f = 0; f < 2; ++f)
        #pragma unroll
        for (int kk = 0; kk < 8; ++kk)
            af[f][kk] = *(const bf16x8*)&Ab[(size_t)(m0 + f * 16 + r15) * D_MOD + kk * 32 + 8 * g];

    #pragma unroll
    for (int ntl = 0; ntl < 4; ++ntl) {
        int col = w * 64 + ntl * 16 + r15;
        f32x4 acc0 = {}, acc1 = {};
        #pragma unroll
        for (int kk = 0; kk < 8; ++kk) {
            bf16x8 bfr = *(const bf16x8*)&WTo[(size_t)col * 256 + kk * 32 + 8 * g];
            acc0 = __builtin_amdgcn_mfma_f32_16x16x32_bf16(af[0][kk], bfr, acc0, 0, 0, 0);
            acc1 = __builtin_amdgcn_mfma_f32_16x16x32_bf16(af[1][kk], bfr, acc1, 0, 0, 0);
        }
        float bval = bo[col];
        #pragma unroll
        for (int r = 0; r < 4; ++r) {
            out[(size_t)(m0 + 4 * g + r) * D_MOD + col]      = acc0[r] + bval;
            out[(size_t)(m0 + 16 + 4 * g + r) * D_MOD + col] = acc1[r] + bval;
        }
    }
}

extern "C" void kernel_launch(void* const* d_in, const int* in_sizes, int n_in,
                              void* d_out, int out_size, void* d_ws, size_t ws_size,
                              hipStream_t stream) {
    const float* q_in = (const float*)d_in[0];
    const float* k_in = (const float*)d_in[1];
    const float* v_in = (const float*)d_in[2];
    // d_in[3] = mask: causal tril, applied analytically.
    const float* Wq = (const float*)d_in[4];
    const float* bq = (const float*)d_in[5];
    const float* Wk = (const float*)d_in[6];
    const float* bk = (const float*)d_in[7];
    const float* Wv = (const float*)d_in[8];
    const float* bv = (const float*)d_in[9];
    const float* Wo = (const float*)d_in[10];
    const float* bo = (const float*)d_in[11];
    float* out = (float*)d_out;

    const size_t NTOK = (size_t)BATCH * S_LEN * D_MOD;  // 2M elements
    short* WT = (short*)d_ws;           // 4 x 256 x 256 bf16 = 512 KB
    short* Qp = WT + 4 * 65536;         // packed [bh][s][32], pre-scaled
    short* Kp = Qp + NTOK;              // packed [bh][s][32]
    short* Vt = Kp + NTOK;              // transposed [bh][hd][s]
    short* Ab = Vt + NTOK;              // [b][s][256]

    wtrans_kernel<<<dim3(4, 32), 256, 0, stream>>>(Wq, Wk, Wv, Wo, WT);
    qkv_proj_kernel<<<dim3(256, 3), 256, 0, stream>>>(
        q_in, k_in, v_in, WT, bq, bk, bv, Qp, Kp, Vt);
    attn_kernel<<<1024, 256, 0, stream>>>(Qp, Kp, Vt, Ab);
    out_proj_kernel<<<256, 256, 0, stream>>>(Ab, WT + 3 * 65536, bo, out);
}

// Round 8
// 87.023 us; speedup vs baseline: 1.0074x; 1.0074x over previous
//
#include <hip/hip_runtime.h>
#include <hip/hip_bf16.h>

#define BATCH 4
#define S_LEN 2048
#define D_MOD 256
#define NH 8
#define HDIM 32
#define SCALE_ 0.0625f
#define QLOG2E 0.09016844f   // SCALE_ * log2(e); folded into Q at projection

typedef short bf16x8 __attribute__((ext_vector_type(8)));
typedef short short4v __attribute__((ext_vector_type(4)));
typedef float f32x4 __attribute__((ext_vector_type(4)));

__device__ __forceinline__ short f2bf(float f) {
    __hip_bfloat16 h = __float2bfloat16(f);
    return *reinterpret_cast<short*>(&h);
}

// ---------------------------------------------------------------------------
// K0: W fp32 [k][n] -> WT bf16 [n][k] for Wq,Wk,Wv,Wo.  grid (4, 32).
// ---------------------------------------------------------------------------
__global__ __launch_bounds__(256) void wtrans_kernel(
    const float* __restrict__ Wq, const float* __restrict__ Wk,
    const float* __restrict__ Wv, const float* __restrict__ Wo,
    short* __restrict__ WT)
{
    const int wsel = blockIdx.x;
    const int k0 = blockIdx.y * 8;
    const float* W = wsel == 0 ? Wq : (wsel == 1 ? Wk : (wsel == 2 ? Wv : Wo));
    short* T = WT + (size_t)wsel * 256 * 256;
    int n = threadIdx.x;
    bf16x8 o;
    #pragma unroll
    for (int kk = 0; kk < 8; ++kk)
        o[kk] = f2bf(W[(size_t)(k0 + kk) * 256 + n]);
    *(bf16x8*)&T[(size_t)n * 256 + k0] = o;
}

// ---------------------------------------------------------------------------
// K1: QKV projection, streaming.  Q is PRE-SCALED by SCALE*log2e so the
// attention kernel can use exp2 directly.  Q,K packed [bh][s][32];
// V transposed [bh][hd][s].  grid (256, 3).
// ---------------------------------------------------------------------------
__global__ __launch_bounds__(256) void qkv_proj_kernel(
    const float* __restrict__ q_in, const float* __restrict__ k_in,
    const float* __restrict__ v_in, const short* __restrict__ WT,
    const float* __restrict__ bq, const float* __restrict__ bk,
    const float* __restrict__ bv,
    short* __restrict__ Qp, short* __restrict__ Kp, short* __restrict__ Vt)
{
    __shared__ short lsA[32][264];
    const int mt = blockIdx.x;
    const int seg = blockIdx.y;
    const float* A = seg == 0 ? q_in : (seg == 1 ? k_in : v_in);
    const short* WTs = WT + (size_t)seg * 65536;
    const float* bias = seg == 0 ? bq : (seg == 1 ? bk : bv);
    const int m0 = mt * 32;
    const int tid = threadIdx.x;

    {
        const float4* A4 = (const float4*)(A + (size_t)m0 * D_MOD);
        #pragma unroll
        for (int i = 0; i < 8; ++i) {
            int f4 = tid + i * 256;
            int row = f4 >> 6, c4 = f4 & 63;
            float4 v = A4[f4];
            short4v o;
            o.x = f2bf(v.x); o.y = f2bf(v.y); o.z = f2bf(v.z); o.w = f2bf(v.w);
            *(short4v*)&lsA[row][c4 * 4] = o;
        }
    }
    __syncthreads();

    const int w = tid >> 6, l = tid & 63, g = l >> 4, r15 = l & 15;
    bf16x8 af[2][8];
    #pragma unroll
    for (int f = 0; f < 2; ++f)
        #pragma unroll
        for (int kk = 0; kk < 8; ++kk)
            af[f][kk] = *(const bf16x8*)&lsA[f * 16 + r15][kk * 32 + 8 * g];

    const int bidx = m0 >> 11;
    const int s_base = m0 & (S_LEN - 1);

    #pragma unroll
    for (int ntl = 0; ntl < 4; ++ntl) {
        int col = w * 64 + ntl * 16 + r15;
        f32x4 acc0 = {}, acc1 = {};
        #pragma unroll
        for (int kk = 0; kk < 8; ++kk) {
            bf16x8 b = *(const bf16x8*)&WTs[(size_t)col * 256 + kk * 32 + 8 * g];
            acc0 = __builtin_amdgcn_mfma_f32_16x16x32_bf16(af[0][kk], b, acc0, 0, 0, 0);
            acc1 = __builtin_amdgcn_mfma_f32_16x16x32_bf16(af[1][kk], b, acc1, 0, 0, 0);
        }
        float bval = bias[col];
        int h = col >> 5, hd = col & 31;
        if (seg == 0) {
            short* Outh = Qp + ((size_t)(bidx * NH + h) * S_LEN) * HDIM;
            #pragma unroll
            for (int r = 0; r < 4; ++r) {
                int s0 = s_base + 4 * g + r;
                Outh[(size_t)s0 * HDIM + hd]        = f2bf((acc0[r] + bval) * QLOG2E);
                Outh[(size_t)(s0 + 16) * HDIM + hd] = f2bf((acc1[r] + bval) * QLOG2E);
            }
        } else if (seg == 1) {
            short* Outh = Kp + ((size_t)(bidx * NH + h) * S_LEN) * HDIM;
            #pragma unroll
            for (int r = 0; r < 4; ++r) {
                int s0 = s_base + 4 * g + r;
                Outh[(size_t)s0 * HDIM + hd]        = f2bf(acc0[r] + bval);
                Outh[(size_t)(s0 + 16) * HDIM + hd] = f2bf(acc1[r] + bval);
            }
        } else {
            short* Vh = Vt + ((size_t)(bidx * NH + h) * HDIM + hd) * S_LEN;
            short4v o0, o1;
            #pragma unroll
            for (int r = 0; r < 4; ++r) { o0[r] = f2bf(acc0[r] + bval); o1[r] = f2bf(acc1[r] + bval); }
            size_t s = s_base + 4 * g;
            *(short4v*)&Vh[s]      = o0;
            *(short4v*)&Vh[s + 16] = o1;
        }
    }
}

// ---------------------------------------------------------------------------
// K2: causal attention, PAIRED q-tiles {63-t, t} for uniform block work;
// K/V fragments loaded once and shared by both tiles with SHORT live ranges
// (no forced occupancy bound -> no spill).  grid 1024.
// ---------------------------------------------------------------------------
__global__ __launch_bounds__(256) void attn_kernel(
    const short* __restrict__ Qp, const short* __restrict__ Kp,
    const short* __restrict__ Vt, short* __restrict__ Ab)
{
    __shared__ short pl[4][64][72];            // 36,864 B; unioned with comb
    __shared__ float psl[4][4][16];            // per-wave row sums
    float (*comb)[64][33] = (float(*)[64][33])pl;

    const int idx = blockIdx.x;
    const int bh = 4 * (idx & 7) + ((idx >> 3) & 3);   // XCD-local bh groups
    const int t  = idx >> 5;                   // 0..31
    const int b = bh >> 3, h = bh & 7;
    const int tid = threadIdx.x;
    const int w = tid >> 6, l = tid & 63, g = l >> 4, r15 = l & 15;
    const int q0b = (63 - t) * 32;             // heavy q-tile
    const int q0s = t * 32;                    // light q-tile

    const short* Qph = Qp + (size_t)bh * S_LEN * HDIM;
    const short* Kph = Kp + (size_t)bh * S_LEN * HDIM;
    const short* Vtp = Vt + (size_t)bh * HDIM * S_LEN;

    bf16x8 aqb0 = *(const bf16x8*)&Qph[(size_t)(q0b + r15) * HDIM + 8 * g];
    bf16x8 aqb1 = *(const bf16x8*)&Qph[(size_t)(q0b + 16 + r15) * HDIM + 8 * g];
    bf16x8 aqs0 = *(const bf16x8*)&Qph[(size_t)(q0s + r15) * HDIM + 8 * g];
    bf16x8 aqs1 = *(const bf16x8*)&Qph[(size_t)(q0s + 16 + r15) * HDIM + 8 * g];

    f32x4 ob[2][2] = {}, os[2][2] = {};
    float psb0[4] = {}, psb1[4] = {}, pss0[4] = {}, pss1[4] = {};
    const f32x4 zero = {};
    const int ntb = (q0b + 95) >> 6;
    const int nts = (q0s + 95) >> 6;

    for (int kt = w; kt < ntb; kt += 4) {
        const int k0 = kt * 64;
        const bool son = kt < nts;             // light tile active (uniform)
        const bool fb = (k0 + 63) <= q0b;
        const bool fs = (k0 + 63) <= q0s;

        // QK^T + exp2 + P-store; one K fragment live at a time, shared b/l
        #pragma unroll
        for (int n = 0; n < 4; ++n) {
            const int key = k0 + n * 16 + r15;
            bf16x8 bk = *(const bf16x8*)&Kph[(size_t)(k0 + n * 16 + r15) * HDIM + 8 * g];
            __builtin_amdgcn_s_setprio(1);
            f32x4 s0 = __builtin_amdgcn_mfma_f32_16x16x32_bf16(aqb0, bk, zero, 0, 0, 0);
            f32x4 s1 = __builtin_amdgcn_mfma_f32_16x16x32_bf16(aqb1, bk, zero, 0, 0, 0);
            __builtin_amdgcn_s_setprio(0);
            if (fb) {
                #pragma unroll
                for (int r = 0; r < 4; ++r) {
                    float e0 = exp2f(s0[r]);
                    float e1 = exp2f(s1[r]);
                    psb0[r] += e0; psb1[r] += e1;
                    pl[w][4 * g + r][n * 16 + r15]      = f2bf(e0);
                    pl[w][16 + 4 * g + r][n * 16 + r15] = f2bf(e1);
                }
            } else {
                #pragma unroll
                for (int r = 0; r < 4; ++r) {
                    int qr = q0b + 4 * g + r;
                    float e0 = (key <= qr)      ? exp2f(s0[r]) : 0.0f;
                    float e1 = (key <= qr + 16) ? exp2f(s1[r]) : 0.0f;
                    psb0[r] += e0; psb1[r] += e1;
                    pl[w][4 * g + r][n * 16 + r15]      = f2bf(e0);
                    pl[w][16 + 4 * g + r][n * 16 + r15] = f2bf(e1);
                }
            }
            if (son) {
                __builtin_amdgcn_s_setprio(1);
                f32x4 u0 = __builtin_amdgcn_mfma_f32_16x16x32_bf16(aqs0, bk, zero, 0, 0, 0);
                f32x4 u1 = __builtin_amdgcn_mfma_f32_16x16x32_bf16(aqs1, bk, zero, 0, 0, 0);
                __builtin_amdgcn_s_setprio(0);
                if (fs) {
                    #pragma unroll
                    for (int r = 0; r < 4; ++r) {
                        float e0 = exp2f(u0[r]);
                        float e1 = exp2f(u1[r]);
                        pss0[r] += e0; pss1[r] += e1;
                        pl[w][32 + 4 * g + r][n * 16 + r15] = f2bf(e0);
                        pl[w][48 + 4 * g + r][n * 16 + r15] = f2bf(e1);
                    }
                } else {
                    #pragma unroll
                    for (int r = 0; r < 4; ++r) {
                        int qr = q0s + 4 * g + r;
                        float e0 = (key <= qr)      ? exp2f(u0[r]) : 0.0f;
                        float e1 = (key <= qr + 16) ? exp2f(u1[r]) : 0.0f;
                        pss0[r] += e0; pss1[r] += e1;
                        pl[w][32 + 4 * g + r][n * 16 + r15] = f2bf(e0);
                        pl[w][48 + 4 * g + r][n * 16 + r15] = f2bf(e1);
                    }
                }
            }
        }

        // PV: one V fragment live at a time, shared by heavy + light
        #pragma unroll
        for (int ks = 0; ks < 2; ++ks) {
            bf16x8 pb0 = *(const bf16x8*)&pl[w][r15][ks * 32 + 8 * g];
            bf16x8 pb1 = *(const bf16x8*)&pl[w][16 + r15][ks * 32 + 8 * g];
            bf16x8 pc0, pc1;
            if (son) {
                pc0 = *(const bf16x8*)&pl[w][32 + r15][ks * 32 + 8 * g];
                pc1 = *(const bf16x8*)&pl[w][48 + r15][ks * 32 + 8 * g];
            }
            #pragma unroll
            for (int n2 = 0; n2 < 2; ++n2) {
                bf16x8 bv = *(const bf16x8*)&Vtp[(size_t)(n2 * 16 + r15) * S_LEN + k0 + ks * 32 + 8 * g];
                __builtin_amdgcn_s_setprio(1);
                ob[0][n2] = __builtin_amdgcn_mfma_f32_16x16x32_bf16(pb0, bv, ob[0][n2], 0, 0, 0);
                ob[1][n2] = __builtin_amdgcn_mfma_f32_16x16x32_bf16(pb1, bv, ob[1][n2], 0, 0, 0);
                if (son) {
                    os[0][n2] = __builtin_amdgcn_mfma_f32_16x16x32_bf16(pc0, bv, os[0][n2], 0, 0, 0);
                    os[1][n2] = __builtin_amdgcn_mfma_f32_16x16x32_bf16(pc1, bv, os[1][n2], 0, 0, 0);
                }
                __builtin_amdgcn_s_setprio(0);
            }
        }
    }

    // row-sum reduce across the 16 key-lanes of each group
    #pragma unroll
    for (int r = 0; r < 4; ++r) {
        float v0 = psb0[r], v1 = psb1[r], v2 = pss0[r], v3 = pss1[r];
        v0 += __shfl_xor(v0, 1); v1 += __shfl_xor(v1, 1); v2 += __shfl_xor(v2, 1); v3 += __shfl_xor(v3, 1);
        v0 += __shfl_xor(v0, 2); v1 += __shfl_xor(v1, 2); v2 += __shfl_xor(v2, 2); v3 += __shfl_xor(v3, 2);
        v0 += __shfl_xor(v0, 4); v1 += __shfl_xor(v1, 4); v2 += __shfl_xor(v2, 4); v3 += __shfl_xor(v3, 4);
        v0 += __shfl_xor(v0, 8); v1 += __shfl_xor(v1, 8); v2 += __shfl_xor(v2, 8); v3 += __shfl_xor(v3, 8);
        psb0[r] = v0; psb1[r] = v1; pss0[r] = v2; pss1[r] = v3;
    }
    if (r15 == 0) {
        #pragma unroll
        for (int r = 0; r < 4; ++r) {
            psl[w][0][4 * g + r] = psb0[r];
            psl[w][1][4 * g + r] = psb1[r];
            psl[w][2][4 * g + r] = pss0[r];
            psl[w][3][4 * g + r] = pss1[r];
        }
    }
    __syncthreads();   // all PV reads of pl done -> reuse storage as comb

    #pragma unroll
    for (int n2 = 0; n2 < 2; ++n2) {
        #pragma unroll
        for (int r = 0; r < 4; ++r) {
            comb[w][4 * g + r][n2 * 16 + r15]      = ob[0][n2][r];
            comb[w][16 + 4 * g + r][n2 * 16 + r15] = ob[1][n2][r];
            comb[w][32 + 4 * g + r][n2 * 16 + r15] = os[0][n2][r];
            comb[w][48 + 4 * g + r][n2 * 16 + r15] = os[1][n2][r];
        }
    }
    __syncthreads();

    // epilogue: 256 threads cover 64 q-rows x 32 hd (8 floats each)
    {
        int q = tid >> 2, hd0 = (tid & 3) * 8;
        float ps = psl[0][q >> 4][q & 15] + psl[1][q >> 4][q & 15]
                 + psl[2][q >> 4][q & 15] + psl[3][q >> 4][q & 15];
        float inv = __fdividef(1.0f, ps);
        int row = (q < 32) ? (q0b + q) : (q0s + q - 32);
        bf16x8 o;
        #pragma unroll
        for (int j = 0; j < 8; ++j) {
            float v = comb[0][q][hd0 + j] + comb[1][q][hd0 + j]
                    + comb[2][q][hd0 + j] + comb[3][q][hd0 + j];
            o[j] = f2bf(v * inv);
        }
        *(bf16x8*)&Ab[((size_t)b * S_LEN + row) * D_MOD + h * HDIM + hd0] = o;
    }
}

// ---------------------------------------------------------------------------
// K3: output projection, streaming (no LDS).  grid 256.
// ---------------------------------------------------------------------------
__global__ __launch_bounds__(256) void out_proj_kernel(
    const short* __restrict__ Ab, const short* __restrict__ WTo,
    const float* __restrict__ bo, float* __restrict__ out)
{
    const int m0 = blockIdx.x * 32;
    const int tid = threadIdx.x;
    const int w = tid >> 6, l = tid & 63, g = l >> 4, r15 = l & 15;

    bf16x8 af[2][8];
    #pragma unroll
    for (int f = 0; f < 2; ++f)
        #pragma unroll
        for (int kk = 0; kk < 8; ++kk)
            af[f][kk] = *(const bf16x8*)&Ab[(size_t)(m0 + f * 16 + r15) * D_MOD + kk * 32 + 8 * g];

    #pragma unroll
    for (int ntl = 0; ntl < 4; ++ntl) {
        int col = w * 64 + ntl * 16 + r15;
        f32x4 acc0 = {}, acc1 = {};
        #pragma unroll
        for (int kk = 0; kk < 8; ++kk) {
            bf16x8 bfr = *(const bf16x8*)&WTo[(size_t)col * 256 + kk * 32 + 8 * g];
            acc0 = __builtin_amdgcn_mfma_f32_16x16x32_bf16(af[0][kk], bfr, acc0, 0, 0, 0);
            acc1 = __builtin_amdgcn_mfma_f32_16x16x32_bf16(af[1][kk], bfr, acc1, 0, 0, 0);
        }
        float bval = bo[col];
        #pragma unroll
        for (int r = 0; r < 4; ++r) {
            out[(size_t)(m0 + 4 * g + r) * D_MOD + col]      = acc0[r] + bval;
            out[(size_t)(m0 + 16 + 4 * g + r) * D_MOD + col] = acc1[r] + bval;
        }
    }
}

extern "C" void kernel_launch(void* const* d_in, const int* in_sizes, int n_in,
                              void* d_out, int out_size, void* d_ws, size_t ws_size,
                              hipStream_t stream) {
    const float* q_in = (const float*)d_in[0];
    const float* k_in = (const float*)d_in[1];
    const float* v_in = (const float*)d_in[2];
    // d_in[3] = mask: causal tril, applied analytically.
    const float* Wq = (const float*)d_in[4];
    const float* bq = (const float*)d_in[5];
    const float* Wk = (const float*)d_in[6];
    const float* bk = (const float*)d_in[7];
    const float* Wv = (const float*)d_in[8];
    const float* bv = (const float*)d_in[9];
    const float* Wo = (const float*)d_in[10];
    const float* bo = (const float*)d_in[11];
    float* out = (float*)d_out;

    const size_t NTOK = (size_t)BATCH * S_LEN * D_MOD;  // 2M elements
    short* WT = (short*)d_ws;           // 4 x 256 x 256 bf16 = 512 KB
    short* Qp = WT + 4 * 65536;         // packed [bh][s][32], pre-scaled
    short* Kp = Qp + NTOK;              // packed [bh][s][32]
    short* Vt = Kp + NTOK;              // transposed [bh][hd][s]
    short* Ab = Vt + NTOK;              // [b][s][256]

    wtrans_kernel<<<dim3(4, 32), 256, 0, stream>>>(Wq, Wk, Wv, Wo, WT);
    qkv_proj_kernel<<<dim3(256, 3), 256, 0, stream>>>(
        q_in, k_in, v_in, WT, bq, bk, bv, Qp, Kp, Vt);
    attn_kernel<<<1024, 256, 0, stream>>>(Qp, Kp, Vt, Ab);
    out_proj_kernel<<<256, 256, 0, stream>>>(Ab, WT + 3 * 65536, bo, out);
}